// Round 2
// baseline (28.012 us; speedup 1.0000x reference)
//
#include <hip/hip_runtime.h>
#include <cfloat>

#define NS 7
#define NC 256
#define NH 64
#define NW 64
#define NR 128

// One wave per (roi, channel). Lanes index W. Separable max:
// phase 1 = column-max per h-bin (coalesced row loads),
// phase 2 = w-window max over the 7x64 colmax stripe in LDS.
__global__ __launch_bounds__(256) void roi_pool_kernel(
    const float* __restrict__ f,
    const int* __restrict__ rois,
    float* __restrict__ out)
{
    __shared__ float colmax_lds[4][NS][NW];  // 4 waves * 7 * 64 * 4B = 7 KB

    const int lane = threadIdx.x & 63;
    const int wid  = threadIdx.x >> 6;

    const int r  = blockIdx.x >> 6;   // 128 rois
    const int cg = blockIdx.x & 63;   // 64 channel groups
    const int c  = cg * 4 + wid;      // 4 channels per block, 1 per wave

    const int x1 = rois[4 * r + 0];   // H range
    const int y1 = rois[4 * r + 1];   // W range
    const int x2 = rois[4 * r + 2];
    const int y2 = rois[4 * r + 3];
    const int Lh = x2 - x1 + 1;
    const int Lw = y2 - y1 + 1;

    const float* fc = f + (size_t)c * (NH * NW);

    // Phase 1: for each h-bin i, lane (= w offset within ROI) computes
    // max over rows [x1 + i*Lh/7, x1 + ceil((i+1)*Lh/7)).
    for (int i = 0; i < NS; ++i) {
        const int hs = x1 + (i * Lh) / NS;
        const int he = x1 + ((i + 1) * Lh + NS - 1) / NS;
        float m = -FLT_MAX;
        if (lane < Lw) {
            const float* p = fc + hs * NW + y1 + lane;
            for (int h = hs; h < he; ++h) {
                m = fmaxf(m, *p);
                p += NW;
            }
        }
        colmax_lds[wid][i][lane] = m;
    }

    __syncthreads();  // uniform across block (same roi -> same trip counts)

    // Phase 2: lanes 0..48 -> bin (i,j); max over relative w-window of colmax.
    if (lane < NS * NS) {
        const int i  = lane / NS;
        const int j  = lane % NS;
        const int cs = (j * Lw) / NS;
        const int ce = ((j + 1) * Lw + NS - 1) / NS;
        float m = -FLT_MAX;
        #pragma unroll 1
        for (int k = cs; k < ce; ++k)
            m = fmaxf(m, colmax_lds[wid][i][k]);
        out[((size_t)(r * NC + c)) * (NS * NS) + lane] = m;
    }
}

extern "C" void kernel_launch(void* const* d_in, const int* in_sizes, int n_in,
                              void* d_out, int out_size, void* d_ws, size_t ws_size,
                              hipStream_t stream)
{
    const float* feature_map = (const float*)d_in[0];
    const int*   rois        = (const int*)d_in[1];
    float*       out         = (float*)d_out;

    const int grid  = NR * (NC / 4);  // 8192 blocks: (roi, channel-group)
    const int block = 256;

    roi_pool_kernel<<<grid, block, 0, stream>>>(feature_map, rois, out);
}